// Round 4
// baseline (364.580 us; speedup 1.0000x reference)
//
#include <hip/hip_runtime.h>
#include <hip/hip_bf16.h>
#include <math.h>

#define B_DIM   4096
#define IN_DIM  4096
#define OUT_DIM 4096

typedef __attribute__((ext_vector_type(8))) short  short8;   // 8 x bf16 = 4 VGPRs
typedef __attribute__((ext_vector_type(4))) float  floatx4;  // MFMA 16x16 accum

__device__ __forceinline__ ushort f2bf(float f) {
    unsigned b = __float_as_uint(f);
    return (ushort)((b + 0x7fffu + ((b >> 16) & 1u)) >> 16);   // RNE
}

// ---- fused prep: blocks 0..1023: x fp32->bf16 + fp64 column partials
//                  blocks 1024..2047: W fp32->bf16 (flat grid-stride)
__global__ void prep(const float* __restrict__ x, const float* __restrict__ W,
                     ushort* __restrict__ xb, ushort* __restrict__ wb,
                     double* __restrict__ part) {
    int bid = blockIdx.x;
    if (bid < 1024) {
        int c0 = (bid & 3) * 1024 + threadIdx.x * 4;
        int r0 = (bid >> 2) * 16;
        double s0 = 0, s1 = 0, s2 = 0, s3 = 0;
#pragma unroll 4
        for (int r = 0; r < 16; ++r) {
            size_t off = (size_t)(r0 + r) * IN_DIM + c0;
            float4 v = *(const float4*)(x + off);
            ushort4 o;
            o.x = f2bf(v.x); o.y = f2bf(v.y); o.z = f2bf(v.z); o.w = f2bf(v.w);
            *(ushort4*)(xb + off) = o;
            s0 += (double)v.x; s1 += (double)v.y; s2 += (double)v.z; s3 += (double)v.w;
        }
        double* p = part + (size_t)(bid >> 2) * IN_DIM + c0;
        p[0] = s0; p[1] = s1; p[2] = s2; p[3] = s3;
    } else {
        const size_t total = (size_t)OUT_DIM * IN_DIM;
        size_t i = ((size_t)(bid - 1024) * 256 + threadIdx.x) * 4;
        const size_t stride = (size_t)1024 * 256 * 4;
        for (; i < total; i += stride) {
            float4 v = *(const float4*)(W + i);
            ushort4 o;
            o.x = f2bf(v.x); o.y = f2bf(v.y); o.z = f2bf(v.z); o.w = f2bf(v.w);
            *(ushort4*)(wb + i) = o;
        }
    }
}

// ---- fold 256 partial chunks -> xbar = mean(x, axis=0) (fp64), 64 blocks ----
__global__ void xbar_reduce(const double* __restrict__ part, double* __restrict__ xbar) {
    __shared__ double red[256];
    int col   = blockIdx.x * 64 + (threadIdx.x & 63);
    int slice = threadIdx.x >> 6;            // 0..3, 64 partial-chunks each
    double s = 0.0;
    for (int rb = slice * 64; rb < slice * 64 + 64; ++rb)
        s += part[(size_t)rb * IN_DIM + col];
    red[threadIdx.x] = s;
    __syncthreads();
    if (slice == 0) {
        double v = red[threadIdx.x] + red[threadIdx.x + 64]
                 + red[threadIdx.x + 128] + red[threadIdx.x + 192];
        xbar[col] = v * (1.0 / (double)B_DIM);
    }
}

// ---- means[o] = dot(xbar, W[o,:]) + b[o] -> idx[o]  (fp32 W, LLC-warm) ----
__global__ void means_idx(const float* __restrict__ W, const float* __restrict__ bias,
                          const double* __restrict__ xbar, int* __restrict__ idx) {
    __shared__ double red[256];
    int o = blockIdx.x;
    size_t base = (size_t)o * IN_DIM;
    double s = 0.0;
#pragma unroll
    for (int j = 0; j < 4; ++j) {
        int i = j * 1024 + threadIdx.x * 4;
        float4 v = *(const float4*)(W + base + i);
        double2 xv0 = *(const double2*)(xbar + i);
        double2 xv1 = *(const double2*)(xbar + i + 2);
        s += (double)v.x * xv0.x + (double)v.y * xv0.y
           + (double)v.z * xv1.x + (double)v.w * xv1.y;
    }
    red[threadIdx.x] = s;
    __syncthreads();
    for (int st = 128; st > 0; st >>= 1) {
        if (threadIdx.x < st) red[threadIdx.x] += red[threadIdx.x + st];
        __syncthreads();
    }
    if (threadIdx.x == 0) {
        // fp32 mod semantics as in jnp (md==3.0f edge lands in else/sigmoid)
        float mf = (float)(red[0] + (double)bias[o]);
        float md = fmodf(mf, 3.0f);
        if (md < 0.0f) md += 3.0f;
        idx[o] = (int)md;
    }
}

// ---- bf16 MFMA GEMM, BK=64, XOR-swizzled LDS (0 bank conflicts),
//      fused branchless epilogue, s_setprio around MFMA phase ----
__global__ void __launch_bounds__(256) gemm_bt_act(
    const ushort* __restrict__ A,   // [M,K] bf16 bits (x)
    const ushort* __restrict__ Bt,  // [N,K] bf16 bits (W)
    const float*  __restrict__ bias,
    const int*    __restrict__ idx,
    float*        __restrict__ out) {
    __shared__ __align__(16) ushort As[128 * 64];
    __shared__ __align__(16) ushort Bs[128 * 64];

    const int t    = threadIdx.x;
    const int w    = t >> 6;
    const int l    = t & 63;
    const int quad = l >> 4;
    const int lrow = l & 15;
    const int m0   = blockIdx.y * 128;
    const int n0   = blockIdx.x * 128;
    const int m0w  = (w >> 1) * 64;
    const int n0w  = (w & 1) * 64;
    const int K    = IN_DIM;

    // preload epilogue scalars (latency hidden under the K-loop)
    int   idv[4];
    float bvv[4];
#pragma unroll
    for (int ni = 0; ni < 4; ++ni) {
        int col = n0 + n0w + ni * 16 + lrow;
        idv[ni] = idx[col];
        bvv[ni] = bias[col];
    }

    floatx4 acc[4][4] = {};

    for (int k0 = 0; k0 < K; k0 += 64) {
#pragma unroll
        for (int j = 0; j < 4; ++j) {
            int chunk = j * 256 + t;                       // 0..1023
            int r     = chunk >> 3;                        // tile row 0..127
            int kb    = (chunk & 7) ^ (r & 7);             // swizzled k-granule
            int goff  = kb << 3;                           // global k offset (elems)
            int ldsoff = (j * 256 + w * 64) * 8;           // wave-uniform base
            __builtin_amdgcn_global_load_lds(
                (__attribute__((address_space(1))) void*)(A + (size_t)(m0 + r) * K + k0 + goff),
                (__attribute__((address_space(3))) void*)(As + ldsoff), 16, 0, 0);
            __builtin_amdgcn_global_load_lds(
                (__attribute__((address_space(1))) void*)(Bt + (size_t)(n0 + r) * K + k0 + goff),
                (__attribute__((address_space(3))) void*)(Bs + ldsoff), 16, 0, 0);
        }
        __syncthreads();

        asm volatile("s_setprio 1");
#pragma unroll
        for (int s = 0; s < 2; ++s) {
            short8 af[4], bf[4];
#pragma unroll
            for (int mi = 0; mi < 4; ++mi) {
                int r = m0w + mi * 16 + lrow;
                int kb = (s * 4 + quad) ^ (r & 7);
                af[mi] = *(const short8*)&As[r * 64 + kb * 8];
            }
#pragma unroll
            for (int ni = 0; ni < 4; ++ni) {
                int r = n0w + ni * 16 + lrow;
                int kb = (s * 4 + quad) ^ (r & 7);
                bf[ni] = *(const short8*)&Bs[r * 64 + kb * 8];
            }
#pragma unroll
            for (int mi = 0; mi < 4; ++mi)
#pragma unroll
                for (int ni = 0; ni < 4; ++ni)
                    acc[mi][ni] = __builtin_amdgcn_mfma_f32_16x16x32_bf16(
                        af[mi], bf[ni], acc[mi][ni], 0, 0, 0);
        }
        asm volatile("s_setprio 0");
        __syncthreads();
    }

    // epilogue: y = acc + bias[col]; branchless activation by idx[col]
    // C/D mapping: col = lane&15, row = quad*4 + reg
    // relu(y)=max(y,0); sigmoid(y)=rcp(1+exp(-y)); tanh(y)=2*sigmoid(2y)-1
#pragma unroll
    for (int ni = 0; ni < 4; ++ni) {
        int   col     = n0 + n0w + ni * 16 + lrow;
        int   id      = idv[ni];
        float bv      = bvv[ni];
        float a       = (id == 1) ? -2.0f : -1.0f;
        bool  isrelu  = (id == 0);
        bool  istanh  = (id == 1);
#pragma unroll
        for (int mi = 0; mi < 4; ++mi) {
            int rowb = m0 + m0w + mi * 16 + quad * 4;
#pragma unroll
            for (int r = 0; r < 4; ++r) {
                float y   = acc[mi][ni][r] + bv;
                float e   = __expf(a * y);                     // v_exp_f32 path
                float s   = __builtin_amdgcn_rcpf(1.0f + e);   // v_rcp_f32
                float act = istanh ? fmaf(2.0f, s, -1.0f) : s;
                float v   = isrelu ? fmaxf(y, 0.0f) : act;
                out[(size_t)(rowb + r) * OUT_DIM + col] = v;
            }
        }
    }
}

extern "C" void kernel_launch(void* const* d_in, const int* in_sizes, int n_in,
                              void* d_out, int out_size, void* d_ws, size_t ws_size,
                              hipStream_t stream) {
    const float* x = (const float*)d_in[0];
    const float* W = (const float*)d_in[1];
    const float* b = (const float*)d_in[2];
    float* out = (float*)d_out;

    char* ws = (char*)d_ws;
    ushort* xb   = (ushort*)(ws);                       // 32 MB
    ushort* wb   = (ushort*)(ws + (33554432));          // 32 MB
    double* part = (double*)(ws + (67108864));          // 256*4096*8 = 8 MB
    double* xbar = (double*)(ws + (67108864 + 8388608));        // 32 KB
    int*    idx  = (int*)   (ws + (67108864 + 8388608 + 32768)); // 16 KB

    prep<<<2048, 256, 0, stream>>>(x, W, xb, wb, part);
    xbar_reduce<<<64, 256, 0, stream>>>(part, xbar);
    means_idx<<<4096, 256, 0, stream>>>(W, b, xbar, idx);
    gemm_bt_act<<<dim3(32, 32), 256, 0, stream>>>(xb, wb, b, idx, out);
}

// Round 6
// 360.796 us; speedup vs baseline: 1.0105x; 1.0105x over previous
//
#include <hip/hip_runtime.h>
#include <hip/hip_bf16.h>
#include <math.h>

#define B_DIM   4096
#define IN_DIM  4096
#define OUT_DIM 4096

typedef __attribute__((ext_vector_type(8))) short  short8;   // 8 x bf16 = 4 VGPRs
typedef __attribute__((ext_vector_type(4))) float  floatx4;  // MFMA 16x16 accum

__device__ __forceinline__ ushort f2bf(float f) {
    unsigned b = __float_as_uint(f);
    return (ushort)((b + 0x7fffu + ((b >> 16) & 1u)) >> 16);   // RNE
}

// ---- fused: x fp32 -> bf16  AND  fp64 partial column sums of x ----
// grid (4, 256): bx -> 1024-col slab (4 cols/thread), by -> 16-row chunk
__global__ void cvt_x_colsum(const float* __restrict__ x, ushort* __restrict__ xb,
                             double* __restrict__ part) {
    int c0 = blockIdx.x * 1024 + threadIdx.x * 4;
    int r0 = blockIdx.y * 16;
    double s0 = 0, s1 = 0, s2 = 0, s3 = 0;
#pragma unroll 4
    for (int r = 0; r < 16; ++r) {
        size_t off = (size_t)(r0 + r) * IN_DIM + c0;
        float4 v = *(const float4*)(x + off);
        ushort4 o;
        o.x = f2bf(v.x); o.y = f2bf(v.y); o.z = f2bf(v.z); o.w = f2bf(v.w);
        *(ushort4*)(xb + off) = o;
        s0 += (double)v.x; s1 += (double)v.y; s2 += (double)v.z; s3 += (double)v.w;
    }
    double* p = part + (size_t)blockIdx.y * IN_DIM + c0;
    p[0] = s0; p[1] = s1; p[2] = s2; p[3] = s3;
}

// ---- fold 256 partial chunks -> xbar = mean(x, axis=0) (fp64), 64 blocks ----
__global__ void xbar_reduce(const double* __restrict__ part, double* __restrict__ xbar) {
    __shared__ double red[256];
    int col   = blockIdx.x * 64 + (threadIdx.x & 63);
    int slice = threadIdx.x >> 6;            // 0..3, 64 partial-chunks each
    double s = 0.0;
    for (int rb = slice * 64; rb < slice * 64 + 64; ++rb)
        s += part[(size_t)rb * IN_DIM + col];
    red[threadIdx.x] = s;
    __syncthreads();
    if (slice == 0) {
        double v = red[threadIdx.x] + red[threadIdx.x + 64]
                 + red[threadIdx.x + 128] + red[threadIdx.x + 192];
        xbar[col] = v * (1.0 / (double)B_DIM);
    }
}

// ---- fused: W fp32 -> bf16  AND  means[o] = dot(xbar,W[o,:]) + b[o] -> idx[o] ----
__global__ void cvt_w_means(const float* __restrict__ W, const float* __restrict__ bias,
                            const double* __restrict__ xbar, ushort* __restrict__ wb,
                            int* __restrict__ idx) {
    __shared__ double red[256];
    int o = blockIdx.x;
    size_t base = (size_t)o * IN_DIM;
    double s = 0.0;
#pragma unroll
    for (int j = 0; j < 4; ++j) {
        int i = j * 1024 + threadIdx.x * 4;
        float4 v = *(const float4*)(W + base + i);
        ushort4 ob;
        ob.x = f2bf(v.x); ob.y = f2bf(v.y); ob.z = f2bf(v.z); ob.w = f2bf(v.w);
        *(ushort4*)(wb + base + i) = ob;
        double2 xv0 = *(const double2*)(xbar + i);
        double2 xv1 = *(const double2*)(xbar + i + 2);
        s += (double)v.x * xv0.x + (double)v.y * xv0.y
           + (double)v.z * xv1.x + (double)v.w * xv1.y;
    }
    red[threadIdx.x] = s;
    __syncthreads();
    for (int st = 128; st > 0; st >>= 1) {
        if (threadIdx.x < st) red[threadIdx.x] += red[threadIdx.x + st];
        __syncthreads();
    }
    if (threadIdx.x == 0) {
        // fp32 mod semantics as in jnp (md==3.0f edge lands in else/sigmoid)
        float mf = (float)(red[0] + (double)bias[o]);
        float md = fmodf(mf, 3.0f);
        if (md < 0.0f) md += 3.0f;
        idx[o] = (int)md;
    }
}

// ---- bf16 MFMA GEMM, BK=32 single-barrier ping-pong, fused epilogue ----
// 128x128 tile, 4 waves (2x2), wave 64x64 via 4x4 16x16x32 MFMAs.
// Ping-pong: statically distinct LDS buffers; one barrier per K-step. The
// compiler's vmcnt(0)-before-barrier now drains loads issued a full compute
// phase earlier (true prefetch) instead of fresh ones.
#define STAGE(AS, BS, KS)                                                          \
    _Pragma("unroll")                                                              \
    for (int j = 0; j < 2; ++j) {                                                  \
        int chunk = j * 256 + t;                                                   \
        int r     = chunk >> 2;                                                    \
        int kc    = (chunk & 3) << 3;                                              \
        int ldsoff = (j * 256 + w * 64) * 8;                                       \
        __builtin_amdgcn_global_load_lds(                                          \
            (__attribute__((address_space(1))) void*)(A + (size_t)(m0 + r) * K + (KS) * 32 + kc),  \
            (__attribute__((address_space(3))) void*)(AS + ldsoff), 16, 0, 0);     \
        __builtin_amdgcn_global_load_lds(                                          \
            (__attribute__((address_space(1))) void*)(Bt + (size_t)(n0 + r) * K + (KS) * 32 + kc), \
            (__attribute__((address_space(3))) void*)(BS + ldsoff), 16, 0, 0);     \
    }

#define COMPUTE(AS, BS)                                                            \
    {                                                                              \
        short8 af[4], bf[4];                                                       \
        _Pragma("unroll")                                                          \
        for (int mi = 0; mi < 4; ++mi)                                             \
            af[mi] = *(const short8*)&AS[(m0w + mi * 16 + lrow) * 32 + quad * 8];  \
        _Pragma("unroll")                                                          \
        for (int ni = 0; ni < 4; ++ni)                                             \
            bf[ni] = *(const short8*)&BS[(n0w + ni * 16 + lrow) * 32 + quad * 8];  \
        _Pragma("unroll")                                                          \
        for (int mi = 0; mi < 4; ++mi)                                             \
            _Pragma("unroll")                                                      \
            for (int ni = 0; ni < 4; ++ni)                                         \
                acc[mi][ni] = __builtin_amdgcn_mfma_f32_16x16x32_bf16(             \
                    af[mi], bf[ni], acc[mi][ni], 0, 0, 0);                         \
    }

__global__ void __launch_bounds__(256) gemm_bt_act(
    const ushort* __restrict__ A,   // [M,K] bf16 bits (x)
    const ushort* __restrict__ Bt,  // [N,K] bf16 bits (W)
    const float*  __restrict__ bias,
    const int*    __restrict__ idx,
    float*        __restrict__ out) {
    __shared__ __align__(16) ushort As0[128 * 32];
    __shared__ __align__(16) ushort Bs0[128 * 32];
    __shared__ __align__(16) ushort As1[128 * 32];
    __shared__ __align__(16) ushort Bs1[128 * 32];

    const int t    = threadIdx.x;
    const int w    = t >> 6;
    const int l    = t & 63;
    const int quad = l >> 4;
    const int lrow = l & 15;

    // 8x8 supertile swizzle (kept from r3 best; cheap)
    const int b   = blockIdx.y * 32 + blockIdx.x;
    const int sup = b >> 6;
    const int q   = b & 63;
    const int m0  = ((sup >> 2) * 8 + (q >> 3)) * 128;
    const int n0  = ((sup & 3)  * 8 + (q & 7))  * 128;

    const int m0w  = (w >> 1) * 64;
    const int n0w  = (w & 1) * 64;
    const int K    = IN_DIM;

    floatx4 acc[4][4] = {};

    STAGE(As0, Bs0, 0)
    for (int ks = 0; ks < 128; ks += 2) {
        __syncthreads();                       // drains stage(ks) (in flight since last half-iter)
        STAGE(As1, Bs1, ks + 1)                // prefetch next step (always valid: ks+1 <= 127)
        COMPUTE(As0, Bs0)
        __syncthreads();                       // drains stage(ks+1)
        if (ks + 2 < 128) STAGE(As0, Bs0, ks + 2)
        COMPUTE(As1, Bs1)
    }

    // epilogue: y = acc + bias[col]; branchless activation by idx[col]
    // C/D mapping: col = lane&15, row = quad*4 + reg
    // relu(y)=max(y,0); sigmoid(y)=rcp(1+exp(-y)); tanh(y)=2*sigmoid(2y)-1
#pragma unroll
    for (int ni = 0; ni < 4; ++ni) {
        int   col     = n0 + n0w + ni * 16 + lrow;
        int   id      = idx[col];
        float bv      = bias[col];
        float a       = (id == 1) ? -2.0f : -1.0f;
        bool  isrelu  = (id == 0);
        bool  istanh  = (id == 1);
#pragma unroll
        for (int mi = 0; mi < 4; ++mi) {
            int rowb = m0 + m0w + mi * 16 + quad * 4;
#pragma unroll
            for (int r = 0; r < 4; ++r) {
                float y   = acc[mi][ni][r] + bv;
                float e   = __expf(a * y);                     // v_exp_f32 path
                float s   = __builtin_amdgcn_rcpf(1.0f + e);   // v_rcp_f32
                float act = istanh ? fmaf(2.0f, s, -1.0f) : s;
                float v   = isrelu ? fmaxf(y, 0.0f) : act;
                out[(size_t)(rowb + r) * OUT_DIM + col] = v;
            }
        }
    }
}

extern "C" void kernel_launch(void* const* d_in, const int* in_sizes, int n_in,
                              void* d_out, int out_size, void* d_ws, size_t ws_size,
                              hipStream_t stream) {
    const float* x = (const float*)d_in[0];
    const float* W = (const float*)d_in[1];
    const float* b = (const float*)d_in[2];
    float* out = (float*)d_out;

    char* ws = (char*)d_ws;
    ushort* xb   = (ushort*)(ws);                       // 32 MB
    ushort* wb   = (ushort*)(ws + (33554432));          // 32 MB
    double* part = (double*)(ws + (67108864));          // 256*4096*8 = 8 MB
    double* xbar = (double*)(ws + (67108864 + 8388608));        // 32 KB
    int*    idx  = (int*)   (ws + (67108864 + 8388608 + 32768)); // 16 KB

    cvt_x_colsum<<<dim3(4, 256), 256, 0, stream>>>(x, xb, part);
    xbar_reduce<<<64, 256, 0, stream>>>(part, xbar);
    cvt_w_means<<<4096, 256, 0, stream>>>(W, b, xbar, wb, idx);
    gemm_bt_act<<<dim3(32, 32), 256, 0, stream>>>(xb, wb, b, idx, out);
}

// Round 7
// 357.574 us; speedup vs baseline: 1.0196x; 1.0090x over previous
//
#include <hip/hip_runtime.h>
#include <hip/hip_bf16.h>
#include <math.h>

#define B_DIM   4096
#define IN_DIM  4096
#define OUT_DIM 4096

typedef __attribute__((ext_vector_type(8))) short  short8;   // 8 x bf16 = 4 VGPRs
typedef __attribute__((ext_vector_type(4))) float  floatx4;  // MFMA 16x16 accum

__device__ __forceinline__ ushort f2bf(float f) {
    unsigned b = __float_as_uint(f);
    return (ushort)((b + 0x7fffu + ((b >> 16) & 1u)) >> 16);   // RNE
}

// ---- fused: x fp32 -> bf16  AND  fp64 partial column sums of x ----
// grid (4, 256): bx -> 1024-col slab (4 cols/thread), by -> 16-row chunk
__global__ void cvt_x_colsum(const float* __restrict__ x, ushort* __restrict__ xb,
                             double* __restrict__ part) {
    int c0 = blockIdx.x * 1024 + threadIdx.x * 4;
    int r0 = blockIdx.y * 16;
    double s0 = 0, s1 = 0, s2 = 0, s3 = 0;
#pragma unroll 4
    for (int r = 0; r < 16; ++r) {
        size_t off = (size_t)(r0 + r) * IN_DIM + c0;
        float4 v = *(const float4*)(x + off);
        ushort4 o;
        o.x = f2bf(v.x); o.y = f2bf(v.y); o.z = f2bf(v.z); o.w = f2bf(v.w);
        *(ushort4*)(xb + off) = o;
        s0 += (double)v.x; s1 += (double)v.y; s2 += (double)v.z; s3 += (double)v.w;
    }
    double* p = part + (size_t)blockIdx.y * IN_DIM + c0;
    p[0] = s0; p[1] = s1; p[2] = s2; p[3] = s3;
}

// ---- fold 256 partial chunks -> xbar = mean(x, axis=0) (fp64), 64 blocks ----
__global__ void xbar_reduce(const double* __restrict__ part, double* __restrict__ xbar) {
    __shared__ double red[256];
    int col   = blockIdx.x * 64 + (threadIdx.x & 63);
    int slice = threadIdx.x >> 6;            // 0..3, 64 partial-chunks each
    double s = 0.0;
    for (int rb = slice * 64; rb < slice * 64 + 64; ++rb)
        s += part[(size_t)rb * IN_DIM + col];
    red[threadIdx.x] = s;
    __syncthreads();
    if (slice == 0) {
        double v = red[threadIdx.x] + red[threadIdx.x + 64]
                 + red[threadIdx.x + 128] + red[threadIdx.x + 192];
        xbar[col] = v * (1.0 / (double)B_DIM);
    }
}

// ---- fused: W fp32 -> bf16  AND  means[o] = dot(xbar,W[o,:]) + b[o] -> idx[o] ----
__global__ void cvt_w_means(const float* __restrict__ W, const float* __restrict__ bias,
                            const double* __restrict__ xbar, ushort* __restrict__ wb,
                            int* __restrict__ idx) {
    __shared__ double red[256];
    int o = blockIdx.x;
    size_t base = (size_t)o * IN_DIM;
    double s = 0.0;
#pragma unroll
    for (int j = 0; j < 4; ++j) {
        int i = j * 1024 + threadIdx.x * 4;
        float4 v = *(const float4*)(W + base + i);
        ushort4 ob;
        ob.x = f2bf(v.x); ob.y = f2bf(v.y); ob.z = f2bf(v.z); ob.w = f2bf(v.w);
        *(ushort4*)(wb + base + i) = ob;
        double2 xv0 = *(const double2*)(xbar + i);
        double2 xv1 = *(const double2*)(xbar + i + 2);
        s += (double)v.x * xv0.x + (double)v.y * xv0.y
           + (double)v.z * xv1.x + (double)v.w * xv1.y;
    }
    red[threadIdx.x] = s;
    __syncthreads();
    for (int st = 128; st > 0; st >>= 1) {
        if (threadIdx.x < st) red[threadIdx.x] += red[threadIdx.x + st];
        __syncthreads();
    }
    if (threadIdx.x == 0) {
        // fp32 mod semantics as in jnp (md==3.0f edge lands in else/sigmoid)
        float mf = (float)(red[0] + (double)bias[o]);
        float md = fmodf(mf, 3.0f);
        if (md < 0.0f) md += 3.0f;
        idx[o] = (int)md;
    }
}

// ---- bf16 MFMA GEMM: BK=32 single-barrier ping-pong + XOR bank swizzle ----
// 128x128 tile, 4 waves (2x2), wave 64x64 via 4x4 16x16x32 MFMAs.
// Ping-pong (r6, worth -13us): statically distinct LDS buffers, one barrier
// per BK=32 step; the vmcnt(0)-before-barrier drains loads issued a full
// compute phase earlier (true prefetch).
// Swizzle (r3 idea at BK=32, worth -25us): physical granule c = logical ^
// ((row>>1)&3). Bank dword = (r&1)*16 + c*4; the 16 lanes of a quad-group
// then hit each (parity x 4-bank-cluster) cell exactly twice -> 2-way = free.
// Staging permutes 16B granules within a 64B segment (coalescing intact,
// LDS fill linear -> global_load_lds wave-uniform base still honored).
#define STAGE(AS, BS, KS)                                                          \
    _Pragma("unroll")                                                              \
    for (int j = 0; j < 2; ++j) {                                                  \
        int chunk = j * 256 + t;                                                   \
        int r     = chunk >> 2;                                                    \
        int kc    = (((chunk & 3) ^ ((r >> 1) & 3)) << 3);                         \
        int ldsoff = (j * 256 + w * 64) * 8;                                       \
        __builtin_amdgcn_global_load_lds(                                          \
            (__attribute__((address_space(1))) void*)(A + (size_t)(m0 + r) * K + (KS) * 32 + kc),  \
            (__attribute__((address_space(3))) void*)(AS + ldsoff), 16, 0, 0);     \
        __builtin_amdgcn_global_load_lds(                                          \
            (__attribute__((address_space(1))) void*)(Bt + (size_t)(n0 + r) * K + (KS) * 32 + kc), \
            (__attribute__((address_space(3))) void*)(BS + ldsoff), 16, 0, 0);     \
    }

#define COMPUTE(AS, BS)                                                            \
    {                                                                              \
        short8 af[4], bf[4];                                                       \
        _Pragma("unroll")                                                          \
        for (int mi = 0; mi < 4; ++mi) {                                           \
            int r = m0w + mi * 16 + lrow;                                          \
            int c = quad ^ ((r >> 1) & 3);                                         \
            af[mi] = *(const short8*)&AS[r * 32 + c * 8];                          \
        }                                                                          \
        _Pragma("unroll")                                                          \
        for (int ni = 0; ni < 4; ++ni) {                                           \
            int r = n0w + ni * 16 + lrow;                                          \
            int c = quad ^ ((r >> 1) & 3);                                         \
            bf[ni] = *(const short8*)&BS[r * 32 + c * 8];                          \
        }                                                                          \
        _Pragma("unroll")                                                          \
        for (int mi = 0; mi < 4; ++mi)                                             \
            _Pragma("unroll")                                                      \
            for (int ni = 0; ni < 4; ++ni)                                         \
                acc[mi][ni] = __builtin_amdgcn_mfma_f32_16x16x32_bf16(             \
                    af[mi], bf[ni], acc[mi][ni], 0, 0, 0);                         \
    }

__global__ void __launch_bounds__(256) gemm_bt_act(
    const ushort* __restrict__ A,   // [M,K] bf16 bits (x)
    const ushort* __restrict__ Bt,  // [N,K] bf16 bits (W)
    const float*  __restrict__ bias,
    const int*    __restrict__ idx,
    float*        __restrict__ out) {
    __shared__ __align__(16) ushort As0[128 * 32];
    __shared__ __align__(16) ushort Bs0[128 * 32];
    __shared__ __align__(16) ushort As1[128 * 32];
    __shared__ __align__(16) ushort Bs1[128 * 32];

    const int t    = threadIdx.x;
    const int w    = t >> 6;
    const int l    = t & 63;
    const int quad = l >> 4;
    const int lrow = l & 15;

    // 8x8 supertile swizzle (cheap; kept from r3)
    const int b   = blockIdx.y * 32 + blockIdx.x;
    const int sup = b >> 6;
    const int q   = b & 63;
    const int m0  = ((sup >> 2) * 8 + (q >> 3)) * 128;
    const int n0  = ((sup & 3)  * 8 + (q & 7))  * 128;

    const int m0w  = (w >> 1) * 64;
    const int n0w  = (w & 1) * 64;
    const int K    = IN_DIM;

    floatx4 acc[4][4] = {};

    STAGE(As0, Bs0, 0)
    for (int ks = 0; ks < 128; ks += 2) {
        __syncthreads();                       // drains stage(ks) (in flight one full compute phase)
        STAGE(As1, Bs1, ks + 1)                // prefetch next step
        COMPUTE(As0, Bs0)
        __syncthreads();                       // drains stage(ks+1)
        if (ks + 2 < 128) STAGE(As0, Bs0, ks + 2)
        COMPUTE(As1, Bs1)
    }

    // epilogue: y = acc + bias[col]; branchless activation by idx[col]
    // C/D mapping: col = lane&15, row = quad*4 + reg
    // relu(y)=max(y,0); sigmoid(y)=rcp(1+exp(-y)); tanh(y)=2*sigmoid(2y)-1
#pragma unroll
    for (int ni = 0; ni < 4; ++ni) {
        int   col     = n0 + n0w + ni * 16 + lrow;
        int   id      = idx[col];
        float bv      = bias[col];
        float a       = (id == 1) ? -2.0f : -1.0f;
        bool  isrelu  = (id == 0);
        bool  istanh  = (id == 1);
#pragma unroll
        for (int mi = 0; mi < 4; ++mi) {
            int rowb = m0 + m0w + mi * 16 + quad * 4;
#pragma unroll
            for (int r = 0; r < 4; ++r) {
                float y   = acc[mi][ni][r] + bv;
                float e   = __expf(a * y);                     // v_exp_f32 path
                float s   = __builtin_amdgcn_rcpf(1.0f + e);   // v_rcp_f32
                float act = istanh ? fmaf(2.0f, s, -1.0f) : s;
                float v   = isrelu ? fmaxf(y, 0.0f) : act;
                out[(size_t)(rowb + r) * OUT_DIM + col] = v;
            }
        }
    }
}

extern "C" void kernel_launch(void* const* d_in, const int* in_sizes, int n_in,
                              void* d_out, int out_size, void* d_ws, size_t ws_size,
                              hipStream_t stream) {
    const float* x = (const float*)d_in[0];
    const float* W = (const float*)d_in[1];
    const float* b = (const float*)d_in[2];
    float* out = (float*)d_out;

    char* ws = (char*)d_ws;
    ushort* xb   = (ushort*)(ws);                       // 32 MB
    ushort* wb   = (ushort*)(ws + (33554432));          // 32 MB
    double* part = (double*)(ws + (67108864));          // 256*4096*8 = 8 MB
    double* xbar = (double*)(ws + (67108864 + 8388608));        // 32 KB
    int*    idx  = (int*)   (ws + (67108864 + 8388608 + 32768)); // 16 KB

    cvt_x_colsum<<<dim3(4, 256), 256, 0, stream>>>(x, xb, part);
    xbar_reduce<<<64, 256, 0, stream>>>(part, xbar);
    cvt_w_means<<<4096, 256, 0, stream>>>(W, b, xbar, wb, idx);
    gemm_bt_act<<<dim3(32, 32), 256, 0, stream>>>(xb, wb, b, idx, out);
}